// Round 12
// baseline (119.225 us; speedup 1.0000x reference)
//
#include <hip/hip_runtime.h>
#include <cstdint>
#include <cstddef>

// Problem constants (fixed by the reference: N=4096, D=512)
constexpr int N_ROWS = 4096;
constexpr int D      = 512;
constexpr int M      = 8192;   // 2N
constexpr int NTILE  = 64;     // M / 128
constexpr int NBLK   = NTILE * (NTILE + 1) / 2;   // 2080 upper-tri tile pairs
constexpr int BKB    = 128;                       // K-bytes per iter (fp8, K=128)
constexpr int LDSB   = 128 * BKB;                 // bytes per LDS K-buffer (16 KB)

using f32x4 = __attribute__((ext_vector_type(4))) float;
using i32x4 = __attribute__((ext_vector_type(4))) int;
using i32x8 = __attribute__((ext_vector_type(8))) int;

// 16B async global->LDS copy. LDS dest is wave-uniform base + lane*16.
#define ASYNC_CP16(gsrc, ldst)                                                      \
    __builtin_amdgcn_global_load_lds(                                               \
        (const __attribute__((address_space(1))) unsigned int*)(gsrc),              \
        (__attribute__((address_space(3))) unsigned int*)(ldst), 16, 0, 0)

// sum of squares of the 4 fp8 e4m3 bytes in `pk` (selector must be literal)
#define SS_FP8(pk, accum)                                                           \
    do {                                                                            \
        float f0 = __builtin_amdgcn_cvt_f32_fp8((pk), 0);                           \
        float f1 = __builtin_amdgcn_cvt_f32_fp8((pk), 1);                           \
        float f2 = __builtin_amdgcn_cvt_f32_fp8((pk), 2);                           \
        float f3 = __builtin_amdgcn_cvt_f32_fp8((pk), 3);                           \
        (accum) += f0 * f0 + f1 * f1 + f2 * f2 + f3 * f3;                           \
    } while (0)

// ---------------------------------------------------------------------------
// Kernel 1: fused normalize + fp8-quantize + positive-pair logits.
// One wave handles PAIR k: row k (emb_i) and row k+N (emb_j).
// Z rows stored fp8 e4m3, straight layout. diagss from the QUANTIZED values
// (matches MFMA diagonal); pos fp32-exact.
// ---------------------------------------------------------------------------
__global__ __launch_bounds__(256) void normpos_kernel(
    const float* __restrict__ emb_i, const float* __restrict__ emb_j,
    uint8_t* __restrict__ zb, float* __restrict__ diagss,
    float* __restrict__ pos)
{
    const int wave = threadIdx.x >> 6, lane = threadIdx.x & 63;
    const int k = blockIdx.x * 4 + wave;

    const float4* a = (const float4*)(emb_i + (size_t)k * D);
    const float4* b = (const float4*)(emb_j + (size_t)k * D);
    float4 a0 = a[lane * 2], a1 = a[lane * 2 + 1];
    float4 b0 = b[lane * 2], b1 = b[lane * 2 + 1];

    float ssi = a0.x*a0.x + a0.y*a0.y + a0.z*a0.z + a0.w*a0.w
              + a1.x*a1.x + a1.y*a1.y + a1.z*a1.z + a1.w*a1.w;
    float ssj = b0.x*b0.x + b0.y*b0.y + b0.z*b0.z + b0.w*b0.w
              + b1.x*b1.x + b1.y*b1.y + b1.z*b1.z + b1.w*b1.w;
    float dp  = a0.x*b0.x + a0.y*b0.y + a0.z*b0.z + a0.w*b0.w
              + a1.x*b1.x + a1.y*b1.y + a1.z*b1.z + a1.w*b1.w;
    #pragma unroll
    for (int off = 32; off; off >>= 1) {
        ssi += __shfl_xor(ssi, off, 64);
        ssj += __shfl_xor(ssj, off, 64);
        dp  += __shfl_xor(dp,  off, 64);
    }
    const float invi = rsqrtf(ssi), invj = rsqrtf(ssj);

    const float zi[8] = {a0.x*invi, a0.y*invi, a0.z*invi, a0.w*invi,
                         a1.x*invi, a1.y*invi, a1.z*invi, a1.w*invi};
    const float zj[8] = {b0.x*invj, b0.y*invj, b0.z*invj, b0.w*invj,
                         b1.x*invj, b1.y*invj, b1.z*invj, b1.w*invj};

    // quantize to fp8 e4m3 (HW RNE + subnormals), dequant for diag sumsq
    int pi0 = __builtin_amdgcn_cvt_pk_fp8_f32(zi[0], zi[1], 0, false);
    pi0     = __builtin_amdgcn_cvt_pk_fp8_f32(zi[2], zi[3], pi0, true);
    int pi1 = __builtin_amdgcn_cvt_pk_fp8_f32(zi[4], zi[5], 0, false);
    pi1     = __builtin_amdgcn_cvt_pk_fp8_f32(zi[6], zi[7], pi1, true);
    int pj0 = __builtin_amdgcn_cvt_pk_fp8_f32(zj[0], zj[1], 0, false);
    pj0     = __builtin_amdgcn_cvt_pk_fp8_f32(zj[2], zj[3], pj0, true);
    int pj1 = __builtin_amdgcn_cvt_pk_fp8_f32(zj[4], zj[5], 0, false);
    pj1     = __builtin_amdgcn_cvt_pk_fp8_f32(zj[6], zj[7], pj1, true);

    float dssi = 0.f, dssj = 0.f;
    SS_FP8(pi0, dssi);
    SS_FP8(pi1, dssi);
    SS_FP8(pj0, dssj);
    SS_FP8(pj1, dssj);

    const unsigned long long vi =
        ((unsigned long long)(unsigned)pi1 << 32) | (unsigned)pi0;
    const unsigned long long vj =
        ((unsigned long long)(unsigned)pj1 << 32) | (unsigned)pj0;
    *(unsigned long long*)(zb + (size_t)k * D + lane * 8)            = vi;
    *(unsigned long long*)(zb + (size_t)(k + N_ROWS) * D + lane * 8) = vj;

    #pragma unroll
    for (int off = 32; off; off >>= 1) {
        dssi += __shfl_xor(dssi, off, 64);
        dssj += __shfl_xor(dssj, off, 64);
    }
    if (lane == 0) {
        diagss[k]          = dssi;
        diagss[k + N_ROWS] = dssj;
        pos[k]             = 2.0f * dp * invi * invj;
    }
}

// ---------------------------------------------------------------------------
// Kernel 2: symmetric fused sim-GEMM, MX-scaled fp8 K=128 (unit scales) +
// exp + row/col partials. 128x128 tile, 4 waves 2x2, SINGLE-buffered
// 34 KB LDS -> 4 blocks/CU (rounds 10/11: 66 KB dbuf capped occupancy at
// 2 blocks/CU = 17% and the K-loop drains had no cross-block overlap;
// per-block time 26K cyc vs 2.2K cyc of MFMA). 4 K-iterations (fewest
// barrier drains of any tried config). Fragment chunk offsets are
// wave-loop-invariant (R&7 == l15&7). ZERO global atomics; wave-halves
// combined via LDS, stored exactly once.
// ---------------------------------------------------------------------------
__global__ __launch_bounds__(256, 4) void simgemm_kernel(
    const uint8_t* __restrict__ zb, float* __restrict__ partials)
{
    __shared__ i32x4 AsV[LDSB / 16];   // 16 KB
    __shared__ i32x4 BsV[LDSB / 16];   // 16 KB
    __shared__ float rp[4][64];    // per-wave row partials
    __shared__ float cp4[4][64];   // per-wave col partials
    uint8_t* As = (uint8_t*)AsV;
    uint8_t* Bs = (uint8_t*)BsV;

    const int tid  = threadIdx.x;
    const int wave = tid >> 6, lane = tid & 63;
    const int l15  = lane & 15, ks = lane >> 4;

    // Decode linear block id -> (bi, bj), bi <= bj. cum(bi) = bi*(129-bi)/2.
    const int t = blockIdx.x;
    int bi = (int)((129.0f - sqrtf(129.0f * 129.0f - 8.0f * (float)t)) * 0.5f);
    while (bi > 0 && bi * (129 - bi) / 2 > t) --bi;
    while ((bi + 1) * (129 - (bi + 1)) / 2 <= t) ++bi;
    const int bj = bi + (t - bi * (129 - bi) / 2);
    const bool diag = (bi == bj);

    const int wrow = (wave >> 1) * 64, wcol = (wave & 1) * 64;

    // Staging: wave w owns rows [w*32, w*32+32); 4 asyncs per matrix per iter
    // (8 rows of 128 B each). lane l -> row +(l>>3), phys 16B chunk l&7;
    // source logical chunk = (l&7) ^ ((l>>3)&7)  (row&7 == (l>>3)&7).
    const int srow = (lane >> 3);                       // 0..7 within async
    const int scol = ((lane & 7) ^ ((lane >> 3) & 7)) * 16;   // bytes [0,128)
    const uint8_t* gA = zb + (size_t)(bi * 128 + wave * 32 + srow) * D + scol;
    const uint8_t* gB = zb + (size_t)(bj * 128 + wave * 32 + srow) * D + scol;
    uint8_t* lA = As + wave * 32 * BKB;
    uint8_t* lB = Bs + wave * 32 * BKB;

    f32x4 acc[4][4] = {};
    // chunk offsets are loop- and frag-invariant: R&7 == l15&7
    const int sw  = l15 & 7;
    const int co0 = ((ks * 2)     ^ sw) * 16;
    const int co1 = ((ks * 2 + 1) ^ sw) * 16;

    for (int it = 0; it < D / BKB; ++it) {
        if (it > 0) __syncthreads();   // all reads of the buffer done
        const int kc = it * BKB;
        #pragma unroll
        for (int c = 0; c < 4; ++c) {
            ASYNC_CP16(gA + kc + (size_t)c * 8 * D, lA + c * 8 * BKB);
            ASYNC_CP16(gB + kc + (size_t)c * 8 * D, lB + c * 8 * BKB);
        }
        __syncthreads();   // vmcnt(0): buffer staged

        i32x8 af[4], bg[4];
        #pragma unroll
        for (int f = 0; f < 4; ++f) {
            {
                const uint8_t* base = As + (wrow + f * 16 + l15) * BKB;
                i32x4 lo = *(const i32x4*)(base + co0);
                i32x4 hi = *(const i32x4*)(base + co1);
                af[f] = __builtin_shufflevector(lo, hi, 0, 1, 2, 3, 4, 5, 6, 7);
            }
            {
                const uint8_t* base = Bs + (wcol + f * 16 + l15) * BKB;
                i32x4 lo = *(const i32x4*)(base + co0);
                i32x4 hi = *(const i32x4*)(base + co1);
                bg[f] = __builtin_shufflevector(lo, hi, 0, 1, 2, 3, 4, 5, 6, 7);
            }
        }
        #pragma unroll
        for (int i = 0; i < 4; ++i)
            #pragma unroll
            for (int j = 0; j < 4; ++j)
                // fmt 0 = fp8 e4m3 for A and B; unit scales (e8m0 0x7F = 2^0)
                acc[i][j] = __builtin_amdgcn_mfma_scale_f32_16x16x128_f8f6f4(
                    af[i], bg[j], acc[i][j], 0, 0, 0, 0x7F, 0, 0x7F);
    }

    // Epilogue. C/D layout: row = ks*4 + r, col = l15 (within each 16x16).
    // e = exp(sim/T) = exp(2*acc). Per-wave partials -> LDS (rp/cp4 don't
    // alias As/Bs), combine the two waves sharing each row-half / col-half,
    // store exactly once.
    float rowp[4][4] = {};
    #pragma unroll
    for (int j = 0; j < 4; ++j) {
        float cpj = 0.f;
        #pragma unroll
        for (int i = 0; i < 4; ++i)
            #pragma unroll
            for (int r = 0; r < 4; ++r) {
                float e = __expf(2.0f * acc[i][j][r]);
                rowp[i][r] += e;
                cpj += e;
            }
        if (!diag) {
            cpj += __shfl_xor(cpj, 16, 64);
            cpj += __shfl_xor(cpj, 32, 64);
            if (ks == 0) cp4[wave][j * 16 + l15] = cpj;
        }
    }
    #pragma unroll
    for (int i = 0; i < 4; ++i)
        #pragma unroll
        for (int r = 0; r < 4; ++r) {
            float e = rowp[i][r];
            e += __shfl_xor(e, 1, 64);
            e += __shfl_xor(e, 2, 64);
            e += __shfl_xor(e, 4, 64);
            e += __shfl_xor(e, 8, 64);
            if (l15 == 0) rp[wave][i * 16 + ks * 4 + r] = e;
        }
    __syncthreads();

    // rows 0-63 from waves {0,1}, 64-127 from {2,3};
    // cols 0-63 from waves {0,2}, 64-127 from {1,3}.
    float* pA = partials + (size_t)(bi * NTILE + bj) * 128;
    float* pB = partials + (size_t)(bj * NTILE + bi) * 128;
    if (tid < 128) {
        const int h = tid >> 6, rr = tid & 63;
        pA[tid] = rp[h * 2][rr] + rp[h * 2 + 1][rr];
    } else if (!diag) {
        const int c = tid - 128, h = c >> 6, cc = c & 63;
        pB[c] = cp4[h][cc] + cp4[h + 2][cc];
    }
}

// ---------------------------------------------------------------------------
// Kernel 3: per-tile-row reduction of partials + log terms + pos chunk.
// ---------------------------------------------------------------------------
__global__ __launch_bounds__(256) void rowfin_kernel(
    const float* __restrict__ partials, const float* __restrict__ diagss,
    const float* __restrict__ pos, float* __restrict__ lgpart)
{
    const int r  = blockIdx.x;          // tile-row 0..63
    const int ri = threadIdx.x & 127;   // row within tile
    const int ch = threadIdx.x >> 7;    // c-half 0/1
    const float* base = partials + (size_t)r * NTILE * 128 + ri;
    float s = 0.f;
    #pragma unroll
    for (int c = 0; c < 32; ++c)
        s += base[(size_t)(ch * 32 + c) * 128];
    __shared__ float half1[128];
    __shared__ float red[4];
    if (ch == 1) half1[ri] = s;
    __syncthreads();
    float lg = 0.f;
    if (ch == 0) {
        float rs = s + half1[ri];
        int row = r * 128 + ri;
        lg = __logf(rs - __expf(2.0f * diagss[row]));
    }
    if (threadIdx.x < 64)
        lg -= 2.0f * pos[r * 64 + threadIdx.x];
    #pragma unroll
    for (int off = 32; off; off >>= 1) lg += __shfl_xor(lg, off, 64);
    const int wave = threadIdx.x >> 6, lane = threadIdx.x & 63;
    if (lane == 0) red[wave] = lg;
    __syncthreads();
    if (threadIdx.x == 0) lgpart[r] = red[0] + red[1] + red[2] + red[3];
}

// ---------------------------------------------------------------------------
// Kernel 4: loss = sum_r lgpart[r] / 8192   (one wave)
// ---------------------------------------------------------------------------
__global__ __launch_bounds__(64) void loss_kernel(
    const float* __restrict__ lgpart, float* __restrict__ out)
{
    float local = lgpart[threadIdx.x];
    #pragma unroll
    for (int off = 32; off; off >>= 1) local += __shfl_xor(local, off, 64);
    if (threadIdx.x == 0) out[0] = local * (1.0f / 8192.0f);
}

// ---------------------------------------------------------------------------
extern "C" void kernel_launch(void* const* d_in, const int* in_sizes, int n_in,
                              void* d_out, int out_size, void* d_ws, size_t ws_size,
                              hipStream_t stream)
{
    const float* emb_i = (const float*)d_in[0];
    const float* emb_j = (const float*)d_in[1];

    // ws layout: zb fp8 [M][D] (4 MB) | partials f32[64][64][128] (2 MB)
    //            | diagss f32[M] | pos f32[N] | lgpart f32[64]  (~6.05 MB)
    uint8_t* zb = (uint8_t*)d_ws;
    float* partials = (float*)((char*)d_ws + (size_t)M * D);
    float* diagss   = partials + (size_t)NTILE * NTILE * 128;
    float* pos      = diagss + M;
    float* lgpart   = pos + N_ROWS;
    float* out      = (float*)d_out;

    normpos_kernel<<<N_ROWS / 4, 256, 0, stream>>>(emb_i, emb_j, zb, diagss, pos);
    simgemm_kernel<<<NBLK, 256, 0, stream>>>(zb, partials);
    rowfin_kernel<<<NTILE, 256, 0, stream>>>(partials, diagss, pos, lgpart);
    loss_kernel<<<1, 64, 0, stream>>>(lgpart, out);
}

// Round 13
// 106.841 us; speedup vs baseline: 1.1159x; 1.1159x over previous
//
#include <hip/hip_runtime.h>
#include <cstdint>
#include <cstddef>

// Problem constants (fixed by the reference: N=4096, D=512)
constexpr int N_ROWS = 4096;
constexpr int D      = 512;
constexpr int M      = 8192;   // 2N
constexpr int NTILE  = 64;     // M / 128
constexpr int NBLK   = NTILE * (NTILE + 1) / 2;   // 2080 upper-tri tile pairs
constexpr int BKB    = 128;                       // K-bytes per iter (fp8, K=128)
constexpr int LDSB   = 128 * BKB;                 // bytes per LDS K-buffer (16 KB)

using f32x4 = __attribute__((ext_vector_type(4))) float;
using i32x4 = __attribute__((ext_vector_type(4))) int;
using i32x8 = __attribute__((ext_vector_type(8))) int;

// 16B async global->LDS copy. LDS dest is wave-uniform base + lane*16.
#define ASYNC_CP16(gsrc, ldst)                                                      \
    __builtin_amdgcn_global_load_lds(                                               \
        (const __attribute__((address_space(1))) unsigned int*)(gsrc),              \
        (__attribute__((address_space(3))) unsigned int*)(ldst), 16, 0, 0)

// sum of squares of the 4 fp8 e4m3 bytes in `pk` (selector must be literal)
#define SS_FP8(pk, accum)                                                           \
    do {                                                                            \
        float f0 = __builtin_amdgcn_cvt_f32_fp8((pk), 0);                           \
        float f1 = __builtin_amdgcn_cvt_f32_fp8((pk), 1);                           \
        float f2 = __builtin_amdgcn_cvt_f32_fp8((pk), 2);                           \
        float f3 = __builtin_amdgcn_cvt_f32_fp8((pk), 3);                           \
        (accum) += f0 * f0 + f1 * f1 + f2 * f2 + f3 * f3;                           \
    } while (0)

// ---------------------------------------------------------------------------
// Kernel 1: fused normalize + fp8-quantize + positive-pair logits.
// One wave handles PAIR k: row k (emb_i) and row k+N (emb_j).
// ---------------------------------------------------------------------------
__global__ __launch_bounds__(256) void normpos_kernel(
    const float* __restrict__ emb_i, const float* __restrict__ emb_j,
    uint8_t* __restrict__ zb, float* __restrict__ diagss,
    float* __restrict__ pos)
{
    const int wave = threadIdx.x >> 6, lane = threadIdx.x & 63;
    const int k = blockIdx.x * 4 + wave;

    const float4* a = (const float4*)(emb_i + (size_t)k * D);
    const float4* b = (const float4*)(emb_j + (size_t)k * D);
    float4 a0 = a[lane * 2], a1 = a[lane * 2 + 1];
    float4 b0 = b[lane * 2], b1 = b[lane * 2 + 1];

    float ssi = a0.x*a0.x + a0.y*a0.y + a0.z*a0.z + a0.w*a0.w
              + a1.x*a1.x + a1.y*a1.y + a1.z*a1.z + a1.w*a1.w;
    float ssj = b0.x*b0.x + b0.y*b0.y + b0.z*b0.z + b0.w*b0.w
              + b1.x*b1.x + b1.y*b1.y + b1.z*b1.z + b1.w*b1.w;
    float dp  = a0.x*b0.x + a0.y*b0.y + a0.z*b0.z + a0.w*b0.w
              + a1.x*b1.x + a1.y*b1.y + a1.z*b1.z + a1.w*b1.w;
    #pragma unroll
    for (int off = 32; off; off >>= 1) {
        ssi += __shfl_xor(ssi, off, 64);
        ssj += __shfl_xor(ssj, off, 64);
        dp  += __shfl_xor(dp,  off, 64);
    }
    const float invi = rsqrtf(ssi), invj = rsqrtf(ssj);

    const float zi[8] = {a0.x*invi, a0.y*invi, a0.z*invi, a0.w*invi,
                         a1.x*invi, a1.y*invi, a1.z*invi, a1.w*invi};
    const float zj[8] = {b0.x*invj, b0.y*invj, b0.z*invj, b0.w*invj,
                         b1.x*invj, b1.y*invj, b1.z*invj, b1.w*invj};

    // quantize to fp8 e4m3 (HW RNE + subnormals), dequant for diag sumsq
    int pi0 = __builtin_amdgcn_cvt_pk_fp8_f32(zi[0], zi[1], 0, false);
    pi0     = __builtin_amdgcn_cvt_pk_fp8_f32(zi[2], zi[3], pi0, true);
    int pi1 = __builtin_amdgcn_cvt_pk_fp8_f32(zi[4], zi[5], 0, false);
    pi1     = __builtin_amdgcn_cvt_pk_fp8_f32(zi[6], zi[7], pi1, true);
    int pj0 = __builtin_amdgcn_cvt_pk_fp8_f32(zj[0], zj[1], 0, false);
    pj0     = __builtin_amdgcn_cvt_pk_fp8_f32(zj[2], zj[3], pj0, true);
    int pj1 = __builtin_amdgcn_cvt_pk_fp8_f32(zj[4], zj[5], 0, false);
    pj1     = __builtin_amdgcn_cvt_pk_fp8_f32(zj[6], zj[7], pj1, true);

    float dssi = 0.f, dssj = 0.f;
    SS_FP8(pi0, dssi);
    SS_FP8(pi1, dssi);
    SS_FP8(pj0, dssj);
    SS_FP8(pj1, dssj);

    const unsigned long long vi =
        ((unsigned long long)(unsigned)pi1 << 32) | (unsigned)pi0;
    const unsigned long long vj =
        ((unsigned long long)(unsigned)pj1 << 32) | (unsigned)pj0;
    *(unsigned long long*)(zb + (size_t)k * D + lane * 8)            = vi;
    *(unsigned long long*)(zb + (size_t)(k + N_ROWS) * D + lane * 8) = vj;

    #pragma unroll
    for (int off = 32; off; off >>= 1) {
        dssi += __shfl_xor(dssi, off, 64);
        dssj += __shfl_xor(dssj, off, 64);
    }
    if (lane == 0) {
        diagss[k]          = dssi;
        diagss[k + N_ROWS] = dssj;
        pos[k]             = 2.0f * dp * invi * invj;
    }
}

// ---------------------------------------------------------------------------
// Kernel 2: symmetric fused sim-GEMM, MX-scaled fp8 K=128 (unit scales) +
// exp + row/col partials. 128x128 tile, 512 threads = 8 WAVES of 32x64
// (wave grid 4x2). Register budget per wave: acc 2x4x4=32 AGPR + af 16 +
// bg 32 + addressing ~ 100 <= 128 -> 4 waves/SIMD WITHOUT spills (round-12:
// 4-wave 64x64 tiles at (256,4) needed ~190 regs -> 79 MB scratch traffic).
// Double-buffered LDS 67 KB -> 2 blocks/CU = 16 waves/CU (2x round-10 TLP),
// 4 K-iterations (fewest barrier drains). ZERO global atomics; wave partials
// combined via LDS, stored exactly once (rows -> partials[bi][bj],
// symmetric cols -> partials[bj][bi]).
// ---------------------------------------------------------------------------
__global__ __launch_bounds__(512, 4) void simgemm_kernel(
    const uint8_t* __restrict__ zb, float* __restrict__ partials)
{
    __shared__ i32x4 AsV[2 * LDSB / 16];   // 32 KB (2 bufs x 16 KB)
    __shared__ i32x4 BsV[2 * LDSB / 16];   // 32 KB
    __shared__ float rp[8][32];    // per-wave row partials (32 rows/wave)
    __shared__ float cp8[8][64];   // per-wave col partials (64 cols/wave)
    uint8_t* As = (uint8_t*)AsV;
    uint8_t* Bs = (uint8_t*)BsV;

    const int tid  = threadIdx.x;
    const int wave = tid >> 6, lane = tid & 63;
    const int l15  = lane & 15, ks = lane >> 4;

    // Decode linear block id -> (bi, bj), bi <= bj. cum(bi) = bi*(129-bi)/2.
    const int t = blockIdx.x;
    int bi = (int)((129.0f - sqrtf(129.0f * 129.0f - 8.0f * (float)t)) * 0.5f);
    while (bi > 0 && bi * (129 - bi) / 2 > t) --bi;
    while ((bi + 1) * (129 - (bi + 1)) / 2 <= t) ++bi;
    const int bj = bi + (t - bi * (129 - bi) / 2);
    const bool diag = (bi == bj);

    const int wrow = (wave >> 1) * 32;   // 4 row-groups of 32
    const int wcol = (wave & 1) * 64;    // 2 col-halves of 64

    // Staging: wave w owns rows [w*16, w*16+16): 2 asyncs per matrix per iter
    // (8 rows of 128 B each). lane l -> row +(l>>3), phys 16B chunk l&7;
    // source logical chunk = (l&7) ^ ((l>>3)&7).
    const int scol = ((lane & 7) ^ ((lane >> 3) & 7)) * 16;   // bytes [0,128)
    const uint8_t* gA = zb + (size_t)(bi * 128 + wave * 16 + (lane >> 3)) * D + scol;
    const uint8_t* gB = zb + (size_t)(bj * 128 + wave * 16 + (lane >> 3)) * D + scol;
    uint8_t* lA = As + wave * 16 * BKB;   // + it-buffer offset
    uint8_t* lB = Bs + wave * 16 * BKB;

    // Prime buffer 0 (K-bytes [0,128))
    #pragma unroll
    for (int c = 0; c < 2; ++c) {
        ASYNC_CP16(gA + (size_t)c * 8 * D, lA + c * 8 * BKB);
        ASYNC_CP16(gB + (size_t)c * 8 * D, lB + c * 8 * BKB);
    }

    f32x4 acc[2][4] = {};
    // chunk offsets are loop- and frag-invariant: R&7 == l15&7
    const int sw  = l15 & 7;
    const int co0 = ((ks * 2)     ^ sw) * 16;
    const int co1 = ((ks * 2 + 1) ^ sw) * 16;

    for (int it = 0; it < D / BKB; ++it) {
        __syncthreads();   // buffer (it&1) ready; other buffer's reads done

        if (it + 1 < D / BKB) {   // prefetch next K-chunk into other buffer
            const int kc  = (it + 1) * BKB;
            const int off = ((it + 1) & 1) * LDSB;
            #pragma unroll
            for (int c = 0; c < 2; ++c) {
                ASYNC_CP16(gA + kc + (size_t)c * 8 * D, lA + off + c * 8 * BKB);
                ASYNC_CP16(gB + kc + (size_t)c * 8 * D, lB + off + c * 8 * BKB);
            }
        }

        const int cb = (it & 1) * LDSB;
        i32x8 af[2], bg[4];
        #pragma unroll
        for (int f = 0; f < 2; ++f) {
            const uint8_t* base = As + cb + (wrow + f * 16 + l15) * BKB;
            i32x4 lo = *(const i32x4*)(base + co0);
            i32x4 hi = *(const i32x4*)(base + co1);
            af[f] = __builtin_shufflevector(lo, hi, 0, 1, 2, 3, 4, 5, 6, 7);
        }
        #pragma unroll
        for (int f = 0; f < 4; ++f) {
            const uint8_t* base = Bs + cb + (wcol + f * 16 + l15) * BKB;
            i32x4 lo = *(const i32x4*)(base + co0);
            i32x4 hi = *(const i32x4*)(base + co1);
            bg[f] = __builtin_shufflevector(lo, hi, 0, 1, 2, 3, 4, 5, 6, 7);
        }
        #pragma unroll
        for (int i = 0; i < 2; ++i)
            #pragma unroll
            for (int j = 0; j < 4; ++j)
                // fmt 0 = fp8 e4m3 for A and B; unit scales (e8m0 0x7F = 2^0)
                acc[i][j] = __builtin_amdgcn_mfma_scale_f32_16x16x128_f8f6f4(
                    af[i], bg[j], acc[i][j], 0, 0, 0, 0x7F, 0, 0x7F);
    }

    // Epilogue. C/D layout: row = ks*4 + r, col = l15 (within each 16x16).
    // e = exp(sim/T) = exp(2*acc). Per-wave partials -> LDS, combine the
    // waves sharing each row-group (pairs) / col-half (quads), store once.
    float rowp[2][4] = {};
    #pragma unroll
    for (int j = 0; j < 4; ++j) {
        float cpj = 0.f;
        #pragma unroll
        for (int i = 0; i < 2; ++i)
            #pragma unroll
            for (int r = 0; r < 4; ++r) {
                float e = __expf(2.0f * acc[i][j][r]);
                rowp[i][r] += e;
                cpj += e;
            }
        if (!diag) {
            cpj += __shfl_xor(cpj, 16, 64);
            cpj += __shfl_xor(cpj, 32, 64);
            if (ks == 0) cp8[wave][j * 16 + l15] = cpj;
        }
    }
    #pragma unroll
    for (int i = 0; i < 2; ++i)
        #pragma unroll
        for (int r = 0; r < 4; ++r) {
            float e = rowp[i][r];
            e += __shfl_xor(e, 1, 64);
            e += __shfl_xor(e, 2, 64);
            e += __shfl_xor(e, 4, 64);
            e += __shfl_xor(e, 8, 64);
            if (l15 == 0) rp[wave][i * 16 + ks * 4 + r] = e;
        }
    __syncthreads();

    // rows m*32..+32 from waves {2m, 2m+1};
    // cols 0-63 from waves {0,2,4,6}, 64-127 from {1,3,5,7}.
    float* pA = partials + (size_t)(bi * NTILE + bj) * 128;
    float* pB = partials + (size_t)(bj * NTILE + bi) * 128;
    if (tid < 128) {
        const int m = tid >> 5, rr = tid & 31;
        pA[tid] = rp[m * 2][rr] + rp[m * 2 + 1][rr];
    } else if (tid < 256 && !diag) {
        const int c = tid - 128, h = c >> 6, cc = c & 63;
        pB[c] = cp8[h][cc] + cp8[h + 2][cc] + cp8[h + 4][cc] + cp8[h + 6][cc];
    }
}

// ---------------------------------------------------------------------------
// Kernel 3: per-tile-row reduction of partials + log terms + pos chunk.
// ---------------------------------------------------------------------------
__global__ __launch_bounds__(256) void rowfin_kernel(
    const float* __restrict__ partials, const float* __restrict__ diagss,
    const float* __restrict__ pos, float* __restrict__ lgpart)
{
    const int r  = blockIdx.x;          // tile-row 0..63
    const int ri = threadIdx.x & 127;   // row within tile
    const int ch = threadIdx.x >> 7;    // c-half 0/1
    const float* base = partials + (size_t)r * NTILE * 128 + ri;
    float s = 0.f;
    #pragma unroll
    for (int c = 0; c < 32; ++c)
        s += base[(size_t)(ch * 32 + c) * 128];
    __shared__ float half1[128];
    __shared__ float red[4];
    if (ch == 1) half1[ri] = s;
    __syncthreads();
    float lg = 0.f;
    if (ch == 0) {
        float rs = s + half1[ri];
        int row = r * 128 + ri;
        lg = __logf(rs - __expf(2.0f * diagss[row]));
    }
    if (threadIdx.x < 64)
        lg -= 2.0f * pos[r * 64 + threadIdx.x];
    #pragma unroll
    for (int off = 32; off; off >>= 1) lg += __shfl_xor(lg, off, 64);
    const int wave = threadIdx.x >> 6, lane = threadIdx.x & 63;
    if (lane == 0) red[wave] = lg;
    __syncthreads();
    if (threadIdx.x == 0) lgpart[r] = red[0] + red[1] + red[2] + red[3];
}

// ---------------------------------------------------------------------------
// Kernel 4: loss = sum_r lgpart[r] / 8192   (one wave)
// ---------------------------------------------------------------------------
__global__ __launch_bounds__(64) void loss_kernel(
    const float* __restrict__ lgpart, float* __restrict__ out)
{
    float local = lgpart[threadIdx.x];
    #pragma unroll
    for (int off = 32; off; off >>= 1) local += __shfl_xor(local, off, 64);
    if (threadIdx.x == 0) out[0] = local * (1.0f / 8192.0f);
}

// ---------------------------------------------------------------------------
extern "C" void kernel_launch(void* const* d_in, const int* in_sizes, int n_in,
                              void* d_out, int out_size, void* d_ws, size_t ws_size,
                              hipStream_t stream)
{
    const float* emb_i = (const float*)d_in[0];
    const float* emb_j = (const float*)d_in[1];

    // ws layout: zb fp8 [M][D] (4 MB) | partials f32[64][64][128] (2 MB)
    //            | diagss f32[M] | pos f32[N] | lgpart f32[64]  (~6.05 MB)
    uint8_t* zb = (uint8_t*)d_ws;
    float* partials = (float*)((char*)d_ws + (size_t)M * D);
    float* diagss   = partials + (size_t)NTILE * NTILE * 128;
    float* pos      = diagss + M;
    float* lgpart   = pos + N_ROWS;
    float* out      = (float*)d_out;

    normpos_kernel<<<N_ROWS / 4, 256, 0, stream>>>(emb_i, emb_j, zb, diagss, pos);
    simgemm_kernel<<<NBLK, 512, 0, stream>>>(zb, partials);
    rowfin_kernel<<<NTILE, 256, 0, stream>>>(partials, diagss, pos, lgpart);
    loss_kernel<<<1, 64, 0, stream>>>(lgpart, out);
}